// Round 4
// baseline (122.392 us; speedup 1.0000x reference)
//
#include <hip/hip_runtime.h>
#include <hip/hip_bf16.h>
#include <stdint.h>

#define NROW 4096
#define DIM  512
#define NT64 (NROW / 64)              // 64 tiles per dim
#define NTRI (NT64 * (NT64 + 1) / 2)  // 2080 triangular 64x64 tiles
#define NKS  (DIM / 32)               // 16 k-steps of 32

typedef __attribute__((ext_vector_type(8))) short  short8;   // 8 bf16 = 4 VGPRs
typedef __attribute__((ext_vector_type(4))) float  floatx4;  // MFMA 16x16 C/D

__device__ __forceinline__ unsigned short f32_to_bf16_rne(float f) {
    unsigned u = __float_as_uint(f);
    u += 0x7FFFu + ((u >> 16) & 1u);
    return (unsigned short)(u >> 16);
}

// 256 threads: wave w handles row blockIdx*4+w. fp32 row norm, bf16 convert,
// out zeroing (harness poisons d_out/d_ws with 0xAA before every launch).
__global__ __launch_bounds__(256) void prep_kernel(
    const float* __restrict__ X, unsigned short* __restrict__ Xb,
    float* __restrict__ sq, float* __restrict__ out)
{
    const int wave = threadIdx.x >> 6;
    const int lane = threadIdx.x & 63;
    const int row  = blockIdx.x * 4 + wave;
    const float4* xr = (const float4*)(X + (size_t)row * DIM);
    float4 v0 = xr[2 * lane];
    float4 v1 = xr[2 * lane + 1];
    float s = v0.x*v0.x + v0.y*v0.y + v0.z*v0.z + v0.w*v0.w
            + v1.x*v1.x + v1.y*v1.y + v1.z*v1.z + v1.w*v1.w;
    uint4 pk;
    pk.x = f32_to_bf16_rne(v0.x) | ((unsigned)f32_to_bf16_rne(v0.y) << 16);
    pk.y = f32_to_bf16_rne(v0.z) | ((unsigned)f32_to_bf16_rne(v0.w) << 16);
    pk.z = f32_to_bf16_rne(v1.x) | ((unsigned)f32_to_bf16_rne(v1.y) << 16);
    pk.w = f32_to_bf16_rne(v1.z) | ((unsigned)f32_to_bf16_rne(v1.w) << 16);
    *(uint4*)(Xb + (size_t)row * DIM + lane * 8) = pk;
    #pragma unroll
    for (int off = 32; off; off >>= 1) s += __shfl_xor(s, off);
    if (lane == 0) sq[row] = s;
    if (blockIdx.x == 0 && threadIdx.x < 2) out[threadIdx.x] = 0.0f;
}

// One wave per triangular 64x64 Gram tile, fragments straight from L1/L2.
// Explicit 2-stage software pipeline with NAMED stage registers and a
// NON-unrolled K-loop so the compiler cannot collapse the prefetch
// (R3 lesson: full unroll -> loads sunk to use, VGPR 72, serial latency).
__global__ __launch_bounds__(256, 2) void ccsa_kernel(
    const unsigned short* __restrict__ Xb, const float* __restrict__ sq,
    const int* __restrict__ ds, const int* __restrict__ y,
    const int* __restrict__ ncls, const int* __restrict__ ndom,
    float* __restrict__ out)
{
    __shared__ float red[8];

    const int wave = threadIdx.x >> 6;
    const int lane = threadIdx.x & 63;
    const int g    = blockIdx.x * 4 + wave;     // tile id, 0..NTRI-1

    // triangular decode: g -> (it <= jt) on the 64-tile grid
    int r = (int)((sqrtf(8.0f * (float)g + 1.0f) - 1.0f) * 0.5f);
    while ((r + 1) * (r + 2) / 2 <= g) ++r;
    while (r * (r + 1) / 2 > g) --r;
    const int jt   = r;
    const int it   = g - r * (r + 1) / 2;
    const bool diag = (it == jt);
    const int i0 = it * 64;
    const int j0 = jt * 64;

    const int m15  = lane & 15;
    const int quad = lane >> 4;

    // per-lane fragment base: row (i0+m15), k-offset quad*8 (A-layout of
    // mfma_f32_16x16x32_bf16; B identical since B[k][n] = X[n][k]).
    const unsigned short* aptr = Xb + (size_t)(i0 + m15) * DIM + quad * 8;
    const unsigned short* bptr = Xb + (size_t)(j0 + m15) * DIM + quad * 8;

    floatx4 acc[4][4];
    #pragma unroll
    for (int a = 0; a < 4; ++a)
        #pragma unroll
        for (int b = 0; b < 4; ++b)
            acc[a][b] = (floatx4){0.f, 0.f, 0.f, 0.f};

    short8 a0[4], b0[4], a1[4], b1[4];   // two explicit pipeline stages

    #define LOADK(A, B, kt)                                                   \
        do {                                                                  \
            _Pragma("unroll")                                                 \
            for (int tt = 0; tt < 4; ++tt) {                                  \
                A[tt] = *(const short8*)(aptr + tt * 16 * DIM + (kt) * 32);   \
                B[tt] = *(const short8*)(bptr + tt * 16 * DIM + (kt) * 32);   \
            }                                                                 \
        } while (0)

    #define MFMAS(A, B)                                                       \
        do {                                                                  \
            _Pragma("unroll")                                                 \
            for (int tm = 0; tm < 4; ++tm)                                    \
                _Pragma("unroll")                                             \
                for (int tn = 0; tn < 4; ++tn)                                \
                    acc[tm][tn] = __builtin_amdgcn_mfma_f32_16x16x32_bf16(    \
                        A[tm], B[tn], acc[tm][tn], 0, 0, 0);                  \
        } while (0)

    LOADK(a0, b0, 0);
    #pragma unroll 1
    for (int kt = 0; kt < NKS - 2; kt += 2) {
        LOADK(a1, b1, kt + 1);   // prefetch k+1 before computing k
        MFMAS(a0, b0);
        LOADK(a0, b0, kt + 2);   // prefetch k+2 before computing k+1
        MFMAS(a1, b1);
    }
    LOADK(a1, b1, NKS - 1);
    MFMAS(a0, b0);
    MFMAS(a1, b1);
    #undef LOADK
    #undef MFMAS

    // Epilogue: C/D map col=lane&15, row=quad*4+reg (m89/m91 verified)
    float sqj[4]; int yj[4], dsj[4];
    #pragma unroll
    for (int tn = 0; tn < 4; ++tn) {
        const int j = j0 + tn * 16 + m15;
        sqj[tn] = sq[j]; yj[tn] = y[j]; dsj[tn] = ds[j];
    }
    float sa = 0.f, ss = 0.f;
    if (diag) {
        // both orientations inside the tile: original one-sided mask
        #pragma unroll
        for (int tm = 0; tm < 4; ++tm) {
            #pragma unroll
            for (int rr = 0; rr < 4; ++rr) {
                const int i = i0 + tm * 16 + quad * 4 + rr;
                const float sqi = sq[i];
                const int   yi  = y[i];
                const int   dsi = ds[i];
                #pragma unroll
                for (int tn = 0; tn < 4; ++tn) {
                    if (dsi < dsj[tn]) {
                        const float d2   = sqi + sqj[tn] - 2.0f * acc[tm][tn][rr];
                        const float dist = sqrtf(fmaxf(d2, 0.f));
                        if (yi == yj[tn])     sa += dist;
                        else if (yi < yj[tn]) ss += fmaxf(0.f, 1.f - dist);
                    }
                }
            }
        }
    } else {
        // off-diagonal tile: fold (i,j) and (j,i); dist is symmetric and
        // exactly one orientation has d_lt when ds_i != ds_j.
        #pragma unroll
        for (int tm = 0; tm < 4; ++tm) {
            #pragma unroll
            for (int rr = 0; rr < 4; ++rr) {
                const int i = i0 + tm * 16 + quad * 4 + rr;
                const float sqi = sq[i];
                const int   yi  = y[i];
                const int   dsi = ds[i];
                #pragma unroll
                for (int tn = 0; tn < 4; ++tn) {
                    if (dsi != dsj[tn]) {
                        const float d2   = sqi + sqj[tn] - 2.0f * acc[tm][tn][rr];
                        const float dist = sqrtf(fmaxf(d2, 0.f));
                        if (yi == yj[tn]) {
                            sa += dist;
                        } else {
                            const bool take = (dsi < dsj[tn]) ? (yi < yj[tn])
                                                              : (yj[tn] < yi);
                            if (take) ss += fmaxf(0.f, 1.f - dist);
                        }
                    }
                }
            }
        }
    }
    #pragma unroll
    for (int off = 32; off; off >>= 1) {
        sa += __shfl_xor(sa, off);
        ss += __shfl_xor(ss, off);
    }
    if (lane == 0) { red[wave] = sa; red[4 + wave] = ss; }
    __syncthreads();
    if (threadIdx.x == 0) {
        const float tsa = red[0] + red[1] + red[2] + red[3];
        const float tss = red[4] + red[5] + red[6] + red[7];
        const int nc = *ncls, nd = *ndom;
        const float n_sa = (float)(nc * (nd * (nd - 1) / 2));
        const float n_s  = (float)((nc * (nc - 1) / 2) * (nd * (nd - 1) / 2));
        atomicAdd(out + 0, tsa * 0.5f / n_sa);
        atomicAdd(out + 1, tss * 0.5f / n_s);
    }
}

extern "C" void kernel_launch(void* const* d_in, const int* in_sizes, int n_in,
                              void* d_out, int out_size, void* d_ws, size_t ws_size,
                              hipStream_t stream) {
    (void)in_sizes; (void)n_in; (void)out_size; (void)ws_size;
    const float* X  = (const float*)d_in[0];
    const int*   ds = (const int*)d_in[1];
    const int*   y  = (const int*)d_in[2];
    const int*   nc = (const int*)d_in[3];
    const int*   nd = (const int*)d_in[4];
    float* out = (float*)d_out;

    unsigned short* Xb = (unsigned short*)d_ws;                       // 4 MB bf16 X
    float* sq = (float*)((char*)d_ws + (size_t)NROW * DIM * 2);       // 16 KB norms

    prep_kernel<<<NROW / 4, 256, 0, stream>>>(X, Xb, sq, out);
    ccsa_kernel<<<NTRI / 4, 256, 0, stream>>>(Xb, sq, ds, y, nc, nd, out);
}

// Round 5
// 98.898 us; speedup vs baseline: 1.2376x; 1.2376x over previous
//
#include <hip/hip_runtime.h>
#include <hip/hip_bf16.h>
#include <stdint.h>

#define NROW 4096
#define DIM  512
#define BM   128
#define BN   128
#define BK   64
#define NKT  (DIM / BK)   // 8 k-tiles

typedef __attribute__((ext_vector_type(8))) short  short8;   // 8 bf16 = 4 VGPRs
typedef __attribute__((ext_vector_type(4))) float  floatx4;  // MFMA 16x16 C/D

typedef const __attribute__((address_space(1))) void gvoid_t;
typedef __attribute__((address_space(3))) void       svoid_t;

__device__ __forceinline__ unsigned short f32_to_bf16_rne(float f) {
    unsigned u = __float_as_uint(f);
    u += 0x7FFFu + ((u >> 16) & 1u);
    return (unsigned short)(u >> 16);
}

// Pre-swizzled tile-major layout for Xb ("Xpre"):
//   group G = row/8 (8 rows), kt = k/64 slab, within a (G,kt) slab of 512
//   shorts: element [l3][p] (l3=row%8, p=0..7) holds the 16-B chunk of row
//   8G+l3 at k-chunk kt*8 + (p ^ l3).  One staging wave-instr then reads a
//   fully CONTIGUOUS 1 KB (base + lane*16B) -> LDS image identical to what
//   the frag reads already unswizzle.  (R2 staging read 16 scattered 64-B
//   half-lines per instr; this reads 8 whole lines sequentially.)
__global__ __launch_bounds__(256) void prep_kernel(
    const float* __restrict__ X, unsigned short* __restrict__ Xpre,
    float* __restrict__ sq, float* __restrict__ out)
{
    const int wave = threadIdx.x >> 6;
    const int lane = threadIdx.x & 63;
    const int row  = blockIdx.x * 4 + wave;
    const float4* xr = (const float4*)(X + (size_t)row * DIM);
    float4 v0 = xr[2 * lane];
    float4 v1 = xr[2 * lane + 1];
    float s = v0.x*v0.x + v0.y*v0.y + v0.z*v0.z + v0.w*v0.w
            + v1.x*v1.x + v1.y*v1.y + v1.z*v1.z + v1.w*v1.w;
    uint4 pk;
    pk.x = f32_to_bf16_rne(v0.x) | ((unsigned)f32_to_bf16_rne(v0.y) << 16);
    pk.y = f32_to_bf16_rne(v0.z) | ((unsigned)f32_to_bf16_rne(v0.w) << 16);
    pk.z = f32_to_bf16_rne(v1.x) | ((unsigned)f32_to_bf16_rne(v1.y) << 16);
    pk.w = f32_to_bf16_rne(v1.z) | ((unsigned)f32_to_bf16_rne(v1.w) << 16);
    const int G   = row >> 3;
    const int l3r = row & 7;
    const int kt  = lane >> 3;
    const int p   = (lane & 7) ^ l3r;
    *(uint4*)(Xpre + (size_t)G * 4096 + kt * 512 + l3r * 64 + p * 8) = pk;
    #pragma unroll
    for (int off = 32; off; off >>= 1) s += __shfl_xor(s, off);
    if (lane == 0) sq[row] = s;
    if (blockIdx.x == 0 && threadIdx.x < 2) out[threadIdx.x] = 0.0f;
}

// Triangular 128x128 Gram tiles, 512 threads (8 waves, 2x4 grid, 64x32 each),
// LDS double-buffer + single barrier per kt, contiguous 1-KB staging loads.
__global__ __launch_bounds__(512, 4) void ccsa_kernel(
    const unsigned short* __restrict__ Xpre, const float* __restrict__ sq,
    const int* __restrict__ ds, const int* __restrict__ y,
    const int* __restrict__ ncls, const int* __restrict__ ndom,
    float* __restrict__ out)
{
    __shared__ __align__(16) unsigned short As[2][BM * BK];  // 2 x 16 KB
    __shared__ __align__(16) unsigned short Bs[2][BN * BK];  // 2 x 16 KB
    __shared__ float red[16];

    // triangular decode: block t -> (bi_t <= bj_t), 32*33/2 = 528 blocks
    const int t = blockIdx.x;
    int r = (int)((sqrtf(8.0f * (float)t + 1.0f) - 1.0f) * 0.5f);
    while ((r + 1) * (r + 2) / 2 <= t) ++r;
    while (r * (r + 1) / 2 > t) --r;
    const int bj_t = r;
    const int bi_t = t - r * (r + 1) / 2;
    const bool diag = (bi_t == bj_t);
    const int bm0 = bi_t * BM;
    const int bn0 = bj_t * BN;
    const int GA = bm0 >> 3;      // row-group base of A tile
    const int GB = bn0 >> 3;      // row-group base of B tile

    const int tid    = threadIdx.x;
    const int wave   = tid >> 6;
    const int lane   = tid & 63;
    const int warp_m = wave >> 2;       // 0..1 : 64-row band
    const int warp_n = wave & 3;        // 0..3 : 32-col band

    floatx4 acc[4][2];
    #pragma unroll
    for (int a = 0; a < 4; ++a)
        #pragma unroll
        for (int b = 0; b < 2; ++b)
            acc[a][b] = (floatx4){0.f, 0.f, 0.f, 0.f};

    const int m15  = lane & 15;
    const int quad = lane >> 4;
    const int row7 = lane & 7;

    // staging: 16 groups per tile; wave w stages groups {w, w+8} of A and B.
    // src is contiguous 1 KB: (G)*4096 + kt*512 + lane*8 shorts.
    #define STAGE(buf, kt)                                                    \
        do {                                                                  \
            _Pragma("unroll")                                                 \
            for (int is = 0; is < 2; ++is) {                                  \
                const int c = is * 8 + wave;                                  \
                __builtin_amdgcn_global_load_lds(                             \
                    (gvoid_t*)(Xpre + (size_t)(GA + c) * 4096 + (kt) * 512    \
                               + lane * 8),                                   \
                    (svoid_t*)(&As[buf][c * 512 + lane * 8]), 16, 0, 0);      \
                __builtin_amdgcn_global_load_lds(                             \
                    (gvoid_t*)(Xpre + (size_t)(GB + c) * 4096 + (kt) * 512    \
                               + lane * 8),                                   \
                    (svoid_t*)(&Bs[buf][c * 512 + lane * 8]), 16, 0, 0);      \
            }                                                                 \
        } while (0)

    STAGE(0, 0);
    for (int kt = 0; kt < NKT; ++kt) {
        const int cur = kt & 1;
        __syncthreads();                      // drains prev-phase loads
        if (kt + 1 < NKT) STAGE(cur ^ 1, kt + 1);

        #pragma unroll
        for (int kh = 0; kh < 2; ++kh) {
            short8 a[4], b[2];
            const int chunk = (kh * 4 + quad) ^ row7;   // un-swizzle
            #pragma unroll
            for (int tt = 0; tt < 4; ++tt) {
                const int rla = warp_m * 64 + tt * 16 + m15;
                a[tt] = *(const short8*)(&As[cur][rla * 64 + chunk * 8]);
            }
            #pragma unroll
            for (int tt = 0; tt < 2; ++tt) {
                const int rlb = warp_n * 32 + tt * 16 + m15;
                b[tt] = *(const short8*)(&Bs[cur][rlb * 64 + chunk * 8]);
            }
            #pragma unroll
            for (int tm = 0; tm < 4; ++tm)
                #pragma unroll
                for (int tn = 0; tn < 2; ++tn)
                    acc[tm][tn] = __builtin_amdgcn_mfma_f32_16x16x32_bf16(
                        a[tm], b[tn], acc[tm][tn], 0, 0, 0);
        }
    }
    #undef STAGE

    // Epilogue: C/D map col=lane&15, row=quad*4+reg (m89/m91 verified)
    float sqj[2]; int yj[2], dsj[2];
    #pragma unroll
    for (int tn = 0; tn < 2; ++tn) {
        const int j = bn0 + warp_n * 32 + tn * 16 + m15;
        sqj[tn] = sq[j]; yj[tn] = y[j]; dsj[tn] = ds[j];
    }
    float sa = 0.f, ss = 0.f;
    if (diag) {
        #pragma unroll
        for (int tm = 0; tm < 4; ++tm) {
            #pragma unroll
            for (int rr = 0; rr < 4; ++rr) {
                const int i = bm0 + warp_m * 64 + tm * 16 + quad * 4 + rr;
                const float sqi = sq[i];
                const int   yi  = y[i];
                const int   dsi = ds[i];
                #pragma unroll
                for (int tn = 0; tn < 2; ++tn) {
                    if (dsi < dsj[tn]) {
                        const float d2   = sqi + sqj[tn] - 2.0f * acc[tm][tn][rr];
                        const float dist = sqrtf(fmaxf(d2, 0.f));
                        if (yi == yj[tn])     sa += dist;
                        else if (yi < yj[tn]) ss += fmaxf(0.f, 1.f - dist);
                    }
                }
            }
        }
    } else {
        // off-diagonal: fold both orientations (dist symmetric; exactly one
        // orientation has d_lt when ds_i != ds_j)
        #pragma unroll
        for (int tm = 0; tm < 4; ++tm) {
            #pragma unroll
            for (int rr = 0; rr < 4; ++rr) {
                const int i = bm0 + warp_m * 64 + tm * 16 + quad * 4 + rr;
                const float sqi = sq[i];
                const int   yi  = y[i];
                const int   dsi = ds[i];
                #pragma unroll
                for (int tn = 0; tn < 2; ++tn) {
                    if (dsi != dsj[tn]) {
                        const float d2   = sqi + sqj[tn] - 2.0f * acc[tm][tn][rr];
                        const float dist = sqrtf(fmaxf(d2, 0.f));
                        if (yi == yj[tn]) {
                            sa += dist;
                        } else {
                            const bool take = (dsi < dsj[tn]) ? (yi < yj[tn])
                                                              : (yj[tn] < yi);
                            if (take) ss += fmaxf(0.f, 1.f - dist);
                        }
                    }
                }
            }
        }
    }
    #pragma unroll
    for (int off = 32; off; off >>= 1) {
        sa += __shfl_xor(sa, off);
        ss += __shfl_xor(ss, off);
    }
    if (lane == 0) { red[wave] = sa; red[8 + wave] = ss; }
    __syncthreads();
    if (tid == 0) {
        float tsa = 0.f, tss = 0.f;
        #pragma unroll
        for (int w = 0; w < 8; ++w) { tsa += red[w]; tss += red[8 + w]; }
        const int nc = *ncls, nd = *ndom;
        const float n_sa = (float)(nc * (nd * (nd - 1) / 2));
        const float n_s  = (float)((nc * (nc - 1) / 2) * (nd * (nd - 1) / 2));
        atomicAdd(out + 0, tsa * 0.5f / n_sa);
        atomicAdd(out + 1, tss * 0.5f / n_s);
    }
}

extern "C" void kernel_launch(void* const* d_in, const int* in_sizes, int n_in,
                              void* d_out, int out_size, void* d_ws, size_t ws_size,
                              hipStream_t stream) {
    (void)in_sizes; (void)n_in; (void)out_size; (void)ws_size;
    const float* X  = (const float*)d_in[0];
    const int*   ds = (const int*)d_in[1];
    const int*   y  = (const int*)d_in[2];
    const int*   nc = (const int*)d_in[3];
    const int*   nd = (const int*)d_in[4];
    float* out = (float*)d_out;

    unsigned short* Xpre = (unsigned short*)d_ws;                     // 4 MB bf16
    float* sq = (float*)((char*)d_ws + (size_t)NROW * DIM * 2);       // 16 KB norms

    prep_kernel<<<NROW / 4, 256, 0, stream>>>(X, Xpre, sq, out);
    const int ntiles = NROW / BM;                                     // 32
    const int nblocks = ntiles * (ntiles + 1) / 2;                    // 528
    ccsa_kernel<<<nblocks, 512, 0, stream>>>(Xpre, sq, ds, y, nc, nd, out);
}